// Round 1
// baseline (45.243 us; speedup 1.0000x reference)
//
#include <hip/hip_runtime.h>
#include <math.h>

constexpr int D     = 1024;
constexpr int NEXP  = 4;
constexpr int TOPK  = 32;
constexpr int NLTS  = 8192;
constexpr int EPP   = NLTS / NEXP;   // 2048 entries per expert

// One block per token. 256 threads = 4 waves.
__global__ __launch_bounds__(256) void slts_kernel(
    const float* __restrict__ h,
    const float* __restrict__ lts,
    const float* __restrict__ Wr,
    const float* __restrict__ br,
    float* __restrict__ out_res,
    float* __restrict__ out_ew)
{
    const int tok  = blockIdx.x;
    const int tid  = threadIdx.x;
    const int wave = tid >> 6;
    const int lane = tid & 63;

    __shared__ float sh_h[D];
    __shared__ float sh_logits[NEXP];
    __shared__ float sh_scores[TOPK];

    // ---- stage h row into LDS (coalesced float4) ----
    const float4* h4 = reinterpret_cast<const float4*>(h + (size_t)tok * D);
    float4 hv = h4[tid];
    reinterpret_cast<float4*>(sh_h)[tid] = hv;
    __syncthreads();

    // ---- router: wave w computes logit for expert w ----
    if (wave < NEXP) {
        const float* w_row = Wr + (size_t)wave * D;
        float acc = 0.f;
        #pragma unroll
        for (int i = 0; i < D / 64; ++i)
            acc += sh_h[lane + 64 * i] * w_row[lane + 64 * i];
        #pragma unroll
        for (int off = 32; off; off >>= 1)
            acc += __shfl_xor(acc, off);
        if (lane == 0) sh_logits[wave] = acc + br[wave];
    }
    __syncthreads();

    // ---- softmax + argmax over 4 logits (redundant per thread) ----
    const float l0 = sh_logits[0], l1 = sh_logits[1],
                l2 = sh_logits[2], l3 = sh_logits[3];
    const float lm = fmaxf(fmaxf(l0, l1), fmaxf(l2, l3));
    const float e0 = expf(l0 - lm), e1 = expf(l1 - lm),
                e2 = expf(l2 - lm), e3 = expf(l3 - lm);
    const float einv = 1.f / (e0 + e1 + e2 + e3);
    if (tid < NEXP) {
        const float ev = (tid == 0) ? e0 : (tid == 1) ? e1 : (tid == 2) ? e2 : e3;
        out_ew[(size_t)tok * NEXP + tid] = ev * einv;
    }
    // argmax with first-max tie semantics (matches jnp.argmax)
    int   bi = 0;
    float bv = l0;
    if (l1 > bv) { bv = l1; bi = 1; }
    if (l2 > bv) { bv = l2; bi = 2; }
    if (l3 > bv) { bv = l3; bi = 3; }
    int offset = bi * EPP;
    if (offset > NLTS - TOPK) offset = NLTS - TOPK;  // never binds here, but matches ref

    // ---- scores: wave w owns scores 8w..8w+7; 8 lanes per score ----
    {
        const int g  = lane >> 3;   // score group within wave, 0..7
        const int sl = lane & 7;    // sub-lane within group
        const int j  = wave * 8 + g;
        int row = offset + j;
        if (row > NLTS - 1) row = NLTS - 1;  // matches ref clamp (never binds)
        const float4* r4 = reinterpret_cast<const float4*>(lts + (size_t)row * D);
        const float4* s4 = reinterpret_cast<const float4*>(sh_h);
        float acc = 0.f;
        #pragma unroll
        for (int i = 0; i < D / 32; ++i) {   // 32 float4s per 8-lane group
            const float4 a = r4[sl + 8 * i];
            const float4 b = s4[sl + 8 * i];
            acc += a.x * b.x + a.y * b.y + a.z * b.z + a.w * b.w;
        }
        acc += __shfl_xor(acc, 1);
        acc += __shfl_xor(acc, 2);
        acc += __shfl_xor(acc, 4);
        if (sl == 0) sh_scores[j] = acc * (1.f / 32.f);  // 1/sqrt(1024)
    }
    __syncthreads();

    // ---- softmax over 32 scores (redundant per thread, broadcast LDS reads) ----
    float m = -INFINITY;
    #pragma unroll
    for (int j = 0; j < TOPK; ++j) m = fmaxf(m, sh_scores[j]);
    float wj[TOPK];
    float ssum = 0.f;
    #pragma unroll
    for (int j = 0; j < TOPK; ++j) {
        const float e = expf(sh_scores[j] - m);
        wj[j] = e;
        ssum += e;
    }
    const float sinv = 1.f / ssum;

    // ---- weighted sum: thread owns one float4 of the output row ----
    float4 accv = make_float4(0.f, 0.f, 0.f, 0.f);
    const float4* lts4 = reinterpret_cast<const float4*>(lts);
    #pragma unroll
    for (int j = 0; j < TOPK; ++j) {
        const float4 v = lts4[(size_t)(offset + j) * (D / 4) + tid];
        const float w = wj[j] * sinv;
        accv.x += w * v.x;
        accv.y += w * v.y;
        accv.z += w * v.z;
        accv.w += w * v.w;
    }
    reinterpret_cast<float4*>(out_res)[(size_t)tok * (D / 4) + tid] = accv;
}

extern "C" void kernel_launch(void* const* d_in, const int* in_sizes, int n_in,
                              void* d_out, int out_size, void* d_ws, size_t ws_size,
                              hipStream_t stream) {
    const float* h   = (const float*)d_in[0];
    const float* lts = (const float*)d_in[1];
    const float* Wr  = (const float*)d_in[2];
    const float* br  = (const float*)d_in[3];

    const int ntok = in_sizes[0] / D;            // b*t = 4096
    float* out_res = (float*)d_out;              // (b,t,d)
    float* out_ew  = out_res + (size_t)ntok * D; // (b,t,NEXP)

    slts_kernel<<<ntok, 256, 0, stream>>>(h, lts, Wr, br, out_res, out_ew);
}